// Round 7
// baseline (734.787 us; speedup 1.0000x reference)
//
#include <hip/hip_runtime.h>
#include <hip/hip_bf16.h>
#include <math.h>

#define NROW 8192
#define DDIM 256
#define BM 128
#define BN 128
#define BK 128          // bytes of k staged per iteration (fp8)
#define NT_SYM 2080     // 64*65/2 lower-triangular 128x128 tiles
#define NT_FULL 4096
#define NBLOCKS (2 * NT_SYM + NT_FULL)

typedef __attribute__((ext_vector_type(4))) float f32x4;
typedef __attribute__((ext_vector_type(4))) int   i32x4;
typedef __attribute__((address_space(3))) unsigned int lds_u32;
typedef const __attribute__((address_space(1))) unsigned int glb_u32;

union frag_cv { i32x4 v; long l[2]; };

// DPP row_ror butterfly add: after ror 1,2,4,8 every lane of each 16-lane row
// holds the row sum. VALU pipe only — no DS traffic.
template <int CTRL>
static __device__ inline float dpp_ror_add(float v) {
    int s = __float_as_int(v);
    int r = __builtin_amdgcn_update_dpp(0, s, CTRL, 0xF, 0xF, true);
    return v + __int_as_float(r);
}
static __device__ inline float row16_sum(float v) {
    v = dpp_ror_add<0x121>(v);
    v = dpp_ror_add<0x122>(v);
    v = dpp_ror_add<0x124>(v);
    v = dpp_ror_add<0x128>(v);
    return v;
}

// Pack 4 floats -> 4 fp8 e4m3 bytes (HW cvt, OCP on gfx950).
static __device__ inline unsigned int pack_fp8x4(float a, float b, float c, float d) {
    int p = __builtin_amdgcn_cvt_pk_fp8_f32(a, b, 0, false);
    p = __builtin_amdgcn_cvt_pk_fp8_f32(c, d, p, true);
    return (unsigned int)p;
}

// One wave per row: L2-normalize, scale by sqrt(2*log2 e) (exp(2s) == exp2(acc)),
// write fp8 rows in FRAGMENT-PERMUTED order:
//   natural k = kh*128 + (2t+u)*32 + quad*8 + b  ->  pos = kh*128 + t*64 + quad*16 + u*8 + b
// so one 16-B granule = the (quad) lane's A/B fragments for ks=2t and 2t+1.
// diag[row] = 2*dot(z1n,z2n) fp32 (exact). Zero-inits rowsums + ticket.
__global__ __launch_bounds__(256) void normalize_kernel(
        const float* __restrict__ h1, const float* __restrict__ h2,
        unsigned char* __restrict__ z1b, unsigned char* __restrict__ z2b,
        float* __restrict__ diag,
        float* __restrict__ rs1, float* __restrict__ rs2,
        float* __restrict__ rbr, float* __restrict__ rbc,
        unsigned int* __restrict__ ticket) {
    int wave = threadIdx.x >> 6;
    int lane = threadIdx.x & 63;
    int row  = blockIdx.x * 4 + wave;
    if (blockIdx.x == 0 && threadIdx.x == 0) *ticket = 0u;
    const float4* p1 = (const float4*)(h1 + (size_t)row * DDIM);
    const float4* p2 = (const float4*)(h2 + (size_t)row * DDIM);
    float4 a = p1[lane];
    float4 b = p2[lane];
    float s1 = a.x*a.x + a.y*a.y + a.z*a.z + a.w*a.w;
    float s2 = b.x*b.x + b.y*b.y + b.z*b.z + b.w*b.w;
    #pragma unroll
    for (int m = 1; m < 64; m <<= 1) { s1 += __shfl_xor(s1, m); s2 += __shfl_xor(s2, m); }
    float r1 = 1.0f / fmaxf(sqrtf(s1), 1e-12f);
    float r2 = 1.0f / fmaxf(sqrtf(s2), 1e-12f);
    float n1x = a.x*r1, n1y = a.y*r1, n1z = a.z*r1, n1w = a.w*r1;
    float n2x = b.x*r2, n2y = b.y*r2, n2z = b.z*r2, n2w = b.w*r2;
    float dt = n1x*n2x + n1y*n2y + n1z*n2z + n1w*n2w;
    #pragma unroll
    for (int m = 1; m < 64; m <<= 1) dt += __shfl_xor(dt, m);
    if (lane == 0) {
        diag[row] = 2.0f * dt;
        rs1[row] = 0.f; rs2[row] = 0.f; rbr[row] = 0.f; rbc[row] = 0.f;
    }
    // lane holds k0 = 4*lane .. +3 (one packed word): compute permuted word slot.
    int kh   = lane >> 5;           // k half (0/1)
    int ks   = (lane >> 3) & 3;     // K=32 step within half
    int t    = ks >> 1, u = ks & 1;
    int quad = (lane >> 1) & 3;
    int wbit = lane & 1;
    int pw   = kh * 32 + t * 16 + quad * 4 + u * 2 + wbit;
    const float SC = 1.69864364f;   // sqrt(2 * log2(e))
    ((unsigned int*)(z1b + (size_t)row * DDIM))[pw] =
        pack_fp8x4(n1x*SC, n1y*SC, n1z*SC, n1w*SC);
    ((unsigned int*)(z2b + (size_t)row * DDIM))[pw] =
        pack_fp8x4(n2x*SC, n2y*SC, n2z*SC, n2w*SC);
}

// Tiles: b < 2080 -> S11 lower-tri; < 4160 -> S22 lower-tri; else S12 full.
// Plain fp8 mfma_f32_16x16x32_fp8_fp8. LDS tiles are FRAGMENT-MAJOR:
//   block(t,s) at t*8192 + s*1024 holds rows 16s..16s+15 x quad-chunks;
//   fragment read (wave, mi, t) = base + lane*16 — lane-linear, so LDS reads
//   are conflict-free by construction (same pattern as the DMA writes, which
//   measured 0 conflicts in R2..R6). DMA fetches the permuted global granules.
// Finalize is fused via a last-block ticket (saves a dispatch).
__global__ __launch_bounds__(256, 4) void expsum_kernel(
        const unsigned char* __restrict__ z1, const unsigned char* __restrict__ z2,
        float* __restrict__ rs1, float* __restrict__ rs2,
        float* __restrict__ rbr, float* __restrict__ rbc,
        const float* __restrict__ diag, float* __restrict__ out,
        unsigned int* __restrict__ ticket) {
    int b = blockIdx.x;
    int kind, t0;
    if (b < NT_SYM)            { kind = 0; t0 = b; }
    else if (b < 2 * NT_SYM)   { kind = 1; t0 = b - NT_SYM; }
    else                       { kind = 2; t0 = b - 2 * NT_SYM; }

    int by, bx;
    const unsigned char *Ap, *Bp;
    float *rowsum, *colsum;
    if (kind == 2) {
        by = t0 >> 6; bx = t0 & 63;
        Ap = z1; Bp = z2; rowsum = rbr; colsum = rbc;
    } else {
        by = (int)((sqrtf(8.0f * (float)t0 + 1.0f) - 1.0f) * 0.5f);
        while ((by + 1) * (by + 2) / 2 <= t0) ++by;
        while (by * (by + 1) / 2 > t0) --by;
        bx = t0 - by * (by + 1) / 2;          // bx <= by
        const unsigned char* z = (kind == 0) ? z1 : z2;
        Ap = z; Bp = z;
        rowsum = (kind == 0) ? rs1 : rs2;
        colsum = (bx == by) ? nullptr : rowsum;
    }

    const int rt = by * BM;
    const int ct = bx * BN;

    __shared__ __align__(16) unsigned char lA[BM * BK];  // 16 KB, fragment-major
    __shared__ __align__(16) unsigned char lB[BN * BK];  // 16 KB

    const int tid  = threadIdx.x;
    const int lane = tid & 63;
    const int wid  = tid >> 6;
    const int wr   = wid >> 1;
    const int wc   = wid & 1;
    const int quad = lane >> 4;
    const int l15  = lane & 15;

    f32x4 acc[4][4];
    #pragma unroll
    for (int mi = 0; mi < 4; ++mi)
        #pragma unroll
        for (int ni = 0; ni < 4; ++ni)
            acc[mi][ni] = (f32x4){0.f, 0.f, 0.f, 0.f};

    for (int kt = 0; kt < DDIM; kt += BK) {
        // Stage: 16 LDS blocks per tile (1024 B each), 4 per wave per tile.
        // Block B2 = t*8 + s: lane fetches permuted-global granule (quad,t)
        // of row 16s + l15.
        #pragma unroll
        for (int i = 0; i < 4; ++i) {
            int B2 = i * 4 + wid;                 // 0..15
            int tt = B2 >> 3, s = B2 & 7;
            size_t go = (size_t)(rt + s * 16 + l15) * DDIM + kt + tt * 64 + quad * 16;
            __builtin_amdgcn_global_load_lds((glb_u32*)(Ap + go),
                                             (lds_u32*)(lA + B2 * 1024), 16, 0, 0);
            size_t gob = (size_t)(ct + s * 16 + l15) * DDIM + kt + tt * 64 + quad * 16;
            __builtin_amdgcn_global_load_lds((glb_u32*)(Bp + gob),
                                             (lds_u32*)(lB + B2 * 1024), 16, 0, 0);
        }
        __syncthreads();
        #pragma unroll
        for (int tt = 0; tt < 2; ++tt) {
            frag_cv va[4], vb[4];
            #pragma unroll
            for (int mi = 0; mi < 4; ++mi)
                va[mi].v = *((const i32x4*)(lA + tt * 8192 + (wr * 4 + mi) * 1024 + lane * 16));
            #pragma unroll
            for (int ni = 0; ni < 4; ++ni)
                vb[ni].v = *((const i32x4*)(lB + tt * 8192 + (wc * 4 + ni) * 1024 + lane * 16));
            #pragma unroll
            for (int mi = 0; mi < 4; ++mi)
                #pragma unroll
                for (int ni = 0; ni < 4; ++ni) {
                    acc[mi][ni] = __builtin_amdgcn_mfma_f32_16x16x32_fp8_fp8(
                        va[mi].l[0], vb[ni].l[0], acc[mi][ni], 0, 0, 0);
                    acc[mi][ni] = __builtin_amdgcn_mfma_f32_16x16x32_fp8_fp8(
                        va[mi].l[1], vb[ni].l[1], acc[mi][ni], 0, 0, 0);
                }
        }
        __syncthreads();
    }

    // C/D layout: col = lane&15, row = quad*4 + reg. acc = 2*log2e*s -> exp2.
    float colpart[4] = {0.f, 0.f, 0.f, 0.f};
    #pragma unroll
    for (int mi = 0; mi < 4; ++mi) {
        #pragma unroll
        for (int r = 0; r < 4; ++r) {
            float rp = 0.f;
            #pragma unroll
            for (int ni = 0; ni < 4; ++ni) {
                float e = exp2f(acc[mi][ni][r]);
                rp += e;
                colpart[ni] += e;
            }
            rp = row16_sum(rp);          // DPP, VALU-pipe only
            if (l15 == 0) {
                int grow = rt + wr * 64 + mi * 16 + quad * 4 + r;
                atomicAdd(&rowsum[grow], rp);
            }
        }
    }
    if (colsum) {
        #pragma unroll
        for (int ni = 0; ni < 4; ++ni) {
            float cp = colpart[ni];
            cp += __shfl_xor(cp, 16);
            cp += __shfl_xor(cp, 32);
            if (lane < 16) {
                int gcol = ct + wc * 64 + ni * 16 + l15;
                atomicAdd(&colsum[gcol], cp);
            }
        }
    }

    // Fused finalize: last block to arrive computes the loss.
    __shared__ int islast;
    __shared__ float s4[4];
    __threadfence();
    if (tid == 0) {
        unsigned int old = atomicAdd(ticket, 1u);
        islast = (old == (unsigned int)(NBLOCKS - 1));
    }
    __syncthreads();
    if (islast) {
        const float E2 = 7.38905609893065f;   // exp(1/tau), tau=0.5
        float accv = 0.f;
        for (int i = tid; i < NROW; i += 256) {
            float a1 = __hip_atomic_load(&rs1[i], __ATOMIC_RELAXED, __HIP_MEMORY_SCOPE_AGENT);
            float a2 = __hip_atomic_load(&rs2[i], __ATOMIC_RELAXED, __HIP_MEMORY_SCOPE_AGENT);
            float b1 = __hip_atomic_load(&rbr[i], __ATOMIC_RELAXED, __HIP_MEMORY_SCOPE_AGENT);
            float b2 = __hip_atomic_load(&rbc[i], __ATOMIC_RELAXED, __HIP_MEMORY_SCOPE_AGENT);
            float den1 = a1 + b1 - E2;
            float den2 = a2 + b2 - E2;
            accv += 0.5f * (logf(den1) + logf(den2)) - diag[i];
        }
        #pragma unroll
        for (int m = 1; m < 64; m <<= 1) accv += __shfl_xor(accv, m);
        if ((tid & 63) == 0) s4[tid >> 6] = accv;
        __syncthreads();
        if (tid == 0)
            out[0] = (s4[0] + s4[1] + s4[2] + s4[3]) * (1.0f / (float)NROW);
    }
}

extern "C" void kernel_launch(void* const* d_in, const int* in_sizes, int n_in,
                              void* d_out, int out_size, void* d_ws, size_t ws_size,
                              hipStream_t stream) {
    const float* h1 = (const float*)d_in[0];
    const float* h2 = (const float*)d_in[1];
    float* out = (float*)d_out;

    char* ws = (char*)d_ws;
    unsigned char* z1b = (unsigned char*)ws;                             // 2 MB
    unsigned char* z2b = (unsigned char*)(ws + (size_t)NROW * DDIM);     // 2 MB
    float* sums = (float*)(ws + (size_t)2 * NROW * DDIM);
    float* rs1  = sums;
    float* rs2  = sums + NROW;
    float* rbr  = sums + 2 * NROW;
    float* rbc  = sums + 3 * NROW;
    float* diag = sums + 4 * NROW;
    unsigned int* ticket = (unsigned int*)(sums + 5 * NROW);

    normalize_kernel<<<NROW / 4, 256, 0, stream>>>(h1, h2, z1b, z2b, diag,
                                                   rs1, rs2, rbr, rbc, ticket);

    expsum_kernel<<<NBLOCKS, 256, 0, stream>>>(z1b, z2b, rs1, rs2, rbr, rbc,
                                               diag, out, ticket);
}

// Round 8
// 174.576 us; speedup vs baseline: 4.2090x; 4.2090x over previous
//
#include <hip/hip_runtime.h>
#include <hip/hip_bf16.h>
#include <math.h>

#define NROW 8192
#define DDIM 256
#define BM 128
#define BN 128
#define NT_SYM 2080     // 64*65/2 lower-triangular 128x128 tiles
#define NT_FULL 4096
#define NBLOCKS (2 * NT_SYM + NT_FULL)

typedef __attribute__((ext_vector_type(4))) float f32x4;
typedef __attribute__((ext_vector_type(4))) int   i32x4;
typedef __attribute__((address_space(3))) unsigned int lds_u32;
typedef const __attribute__((address_space(1))) unsigned int glb_u32;

union frag_cv { i32x4 v; long l[2]; };

// DPP row_ror butterfly add: after ror 1,2,4,8 every lane of each 16-lane row
// holds the row sum. VALU pipe only — no DS traffic.
template <int CTRL>
static __device__ inline float dpp_ror_add(float v) {
    int s = __float_as_int(v);
    int r = __builtin_amdgcn_update_dpp(0, s, CTRL, 0xF, 0xF, true);
    return v + __int_as_float(r);
}
static __device__ inline float row16_sum(float v) {
    v = dpp_ror_add<0x121>(v);
    v = dpp_ror_add<0x122>(v);
    v = dpp_ror_add<0x124>(v);
    v = dpp_ror_add<0x128>(v);
    return v;
}

// Pack 4 floats -> 4 fp8 e4m3 bytes (HW cvt, OCP on gfx950).
static __device__ inline unsigned int pack_fp8x4(float a, float b, float c, float d) {
    int p = __builtin_amdgcn_cvt_pk_fp8_f32(a, b, 0, false);
    p = __builtin_amdgcn_cvt_pk_fp8_f32(c, d, p, true);
    return (unsigned int)p;
}

// TILED z layout: storage block SB(g,t) = 1024 contiguous bytes, g = 16-row
// group (0..511), t = K-64 slice (0..3). Byte (quad*256 + rr*16 + u*8 + b) of
// SB(g,t) holds z_norm[16g+rr][ (2t+u)*32 + quad*8 + b ] — i.e. exactly the
// lane-ordered MFMA fragment block, so expsum's DMA is lane*16 into a
// contiguous 1 KB and LDS reads are lane-linear (0-conflict, R7-validated
// content). One wave per row; lane holds k0=4*lane..+3 -> one u32 store.
// diag[row] = 2*dot(z1n,z2n) fp32 (exact). Zero-inits rowsums.
__global__ __launch_bounds__(256) void normalize_kernel(
        const float* __restrict__ h1, const float* __restrict__ h2,
        unsigned int* __restrict__ z1b, unsigned int* __restrict__ z2b,
        float* __restrict__ diag,
        float* __restrict__ rs1, float* __restrict__ rs2,
        float* __restrict__ rbr, float* __restrict__ rbc) {
    int wave = threadIdx.x >> 6;
    int lane = threadIdx.x & 63;
    int row  = blockIdx.x * 4 + wave;
    const float4* p1 = (const float4*)(h1 + (size_t)row * DDIM);
    const float4* p2 = (const float4*)(h2 + (size_t)row * DDIM);
    float4 a = p1[lane];
    float4 b = p2[lane];
    float s1 = a.x*a.x + a.y*a.y + a.z*a.z + a.w*a.w;
    float s2 = b.x*b.x + b.y*b.y + b.z*b.z + b.w*b.w;
    #pragma unroll
    for (int m = 1; m < 64; m <<= 1) { s1 += __shfl_xor(s1, m); s2 += __shfl_xor(s2, m); }
    float r1 = 1.0f / fmaxf(sqrtf(s1), 1e-12f);
    float r2 = 1.0f / fmaxf(sqrtf(s2), 1e-12f);
    float n1x = a.x*r1, n1y = a.y*r1, n1z = a.z*r1, n1w = a.w*r1;
    float n2x = b.x*r2, n2y = b.y*r2, n2z = b.z*r2, n2w = b.w*r2;
    float dt = n1x*n2x + n1y*n2y + n1z*n2z + n1w*n2w;
    #pragma unroll
    for (int m = 1; m < 64; m <<= 1) dt += __shfl_xor(dt, m);
    if (lane == 0) {
        diag[row] = 2.0f * dt;
        rs1[row] = 0.f; rs2[row] = 0.f; rbr[row] = 0.f; rbc[row] = 0.f;
    }
    // k0 = 4*lane -> (t, u, quad, wbit) in the tiled layout:
    int t    = lane >> 4;           // K-64 slice
    int u    = (lane >> 3) & 1;     // K=32 step within slice
    int quad = (lane >> 1) & 3;
    int wbit = lane & 1;
    int g    = row >> 4, rr = row & 15;
    int pw   = g * 1024 + t * 256 + quad * 64 + rr * 4 + u * 2 + wbit;  // u32 idx
    const float SC = 1.69864364f;   // sqrt(2 * log2(e))
    z1b[pw] = pack_fp8x4(n1x*SC, n1y*SC, n1z*SC, n1w*SC);
    z2b[pw] = pack_fp8x4(n2x*SC, n2y*SC, n2z*SC, n2w*SC);
}

// Tiles: b < 2080 -> S11 lower-tri; < 4160 -> S22 lower-tri; else S12 full.
// Plain fp8 mfma_f32_16x16x32_fp8_fp8. z is pre-tiled (see normalize): each
// DMA instruction copies one full 1024-B storage block (contiguous global,
// lane*16) into the matching LDS block; fragment reads are lane-linear.
// 3-dispatch structure (no fence/ticket — R7 post-mortem).
__global__ __launch_bounds__(256, 4) void expsum_kernel(
        const unsigned char* __restrict__ z1, const unsigned char* __restrict__ z2,
        float* __restrict__ rs1, float* __restrict__ rs2,
        float* __restrict__ rbr, float* __restrict__ rbc) {
    int b = blockIdx.x;
    int kind, t0;
    if (b < NT_SYM)            { kind = 0; t0 = b; }
    else if (b < 2 * NT_SYM)   { kind = 1; t0 = b - NT_SYM; }
    else                       { kind = 2; t0 = b - 2 * NT_SYM; }

    int by, bx;
    const unsigned char *Ap, *Bp;
    float *rowsum, *colsum;
    if (kind == 2) {
        by = t0 >> 6; bx = t0 & 63;
        Ap = z1; Bp = z2; rowsum = rbr; colsum = rbc;
    } else {
        by = (int)((sqrtf(8.0f * (float)t0 + 1.0f) - 1.0f) * 0.5f);
        while ((by + 1) * (by + 2) / 2 <= t0) ++by;
        while (by * (by + 1) / 2 > t0) --by;
        bx = t0 - by * (by + 1) / 2;          // bx <= by
        const unsigned char* z = (kind == 0) ? z1 : z2;
        Ap = z; Bp = z;
        rowsum = (kind == 0) ? rs1 : rs2;
        colsum = (bx == by) ? nullptr : rowsum;
    }

    __shared__ __align__(16) unsigned char lA[BM * 128];  // 16 KB = 16 blocks
    __shared__ __align__(16) unsigned char lB[BN * 128];  // 16 KB

    const int tid  = threadIdx.x;
    const int lane = tid & 63;
    const int wid  = tid >> 6;
    const int wr   = wid >> 1;
    const int wc   = wid & 1;
    const int quad = lane >> 4;
    const int l15  = lane & 15;

    f32x4 acc[4][4];
    #pragma unroll
    for (int mi = 0; mi < 4; ++mi)
        #pragma unroll
        for (int ni = 0; ni < 4; ++ni)
            acc[mi][ni] = (f32x4){0.f, 0.f, 0.f, 0.f};

    for (int kt = 0; kt < 2; ++kt) {          // two K-128 halves
        // Stage 16 blocks per matrix (idx = tt*8 + s), 4 per wave:
        // global = SB(by*8+s, kt*2+tt), fully contiguous 1 KB, lane*16.
        #pragma unroll
        for (int i = 0; i < 4; ++i) {
            int idx = i * 4 + wid;            // 0..15
            int tt = idx >> 3, s = idx & 7;
            const unsigned char* ga = Ap + (((size_t)(by * 8 + s)) << 12)
                                         + (size_t)(kt * 2 + tt) * 1024 + lane * 16;
            __builtin_amdgcn_global_load_lds((glb_u32*)ga,
                                             (lds_u32*)(lA + idx * 1024), 16, 0, 0);
            const unsigned char* gb = Bp + (((size_t)(bx * 8 + s)) << 12)
                                         + (size_t)(kt * 2 + tt) * 1024 + lane * 16;
            __builtin_amdgcn_global_load_lds((glb_u32*)gb,
                                             (lds_u32*)(lB + idx * 1024), 16, 0, 0);
        }
        __syncthreads();
        #pragma unroll
        for (int tt = 0; tt < 2; ++tt) {
            frag_cv va[4], vb[4];
            #pragma unroll
            for (int mi = 0; mi < 4; ++mi)
                va[mi].v = *((const i32x4*)(lA + (tt * 8 + wr * 4 + mi) * 1024 + lane * 16));
            #pragma unroll
            for (int ni = 0; ni < 4; ++ni)
                vb[ni].v = *((const i32x4*)(lB + (tt * 8 + wc * 4 + ni) * 1024 + lane * 16));
            #pragma unroll
            for (int mi = 0; mi < 4; ++mi)
                #pragma unroll
                for (int ni = 0; ni < 4; ++ni) {
                    acc[mi][ni] = __builtin_amdgcn_mfma_f32_16x16x32_fp8_fp8(
                        va[mi].l[0], vb[ni].l[0], acc[mi][ni], 0, 0, 0);
                    acc[mi][ni] = __builtin_amdgcn_mfma_f32_16x16x32_fp8_fp8(
                        va[mi].l[1], vb[ni].l[1], acc[mi][ni], 0, 0, 0);
                }
        }
        __syncthreads();
    }

    const int rt = by * BM;
    const int ct = bx * BN;

    // C/D layout: col = lane&15, row = quad*4 + reg. acc = 2*log2e*s -> exp2.
    float colpart[4] = {0.f, 0.f, 0.f, 0.f};
    #pragma unroll
    for (int mi = 0; mi < 4; ++mi) {
        #pragma unroll
        for (int r = 0; r < 4; ++r) {
            float rp = 0.f;
            #pragma unroll
            for (int ni = 0; ni < 4; ++ni) {
                float e = exp2f(acc[mi][ni][r]);
                rp += e;
                colpart[ni] += e;
            }
            rp = row16_sum(rp);          // DPP, VALU-pipe only
            if (l15 == 0) {
                int grow = rt + wr * 64 + mi * 16 + quad * 4 + r;
                atomicAdd(&rowsum[grow], rp);
            }
        }
    }
    if (colsum) {
        #pragma unroll
        for (int ni = 0; ni < 4; ++ni) {
            float cp = colpart[ni];
            cp += __shfl_xor(cp, 16);
            cp += __shfl_xor(cp, 32);
            if (lane < 16) {
                int gcol = ct + wc * 64 + ni * 16 + l15;
                atomicAdd(&colsum[gcol], cp);
            }
        }
    }
}

// 32 blocks x 256 threads, one row each; block-reduce then one atomicAdd.
__global__ __launch_bounds__(256) void finalize_kernel(
        const float* __restrict__ rs1, const float* __restrict__ rs2,
        const float* __restrict__ rbr, const float* __restrict__ rbc,
        const float* __restrict__ diag, float* __restrict__ out) {
    __shared__ float s4[4];
    const float E2 = 7.38905609893065f;   // exp(1/tau), tau=0.5
    int i = blockIdx.x * 256 + threadIdx.x;
    float den1 = rs1[i] + rbr[i] - E2;
    float den2 = rs2[i] + rbc[i] - E2;
    float v = 0.5f * (logf(den1) + logf(den2)) - diag[i];
    #pragma unroll
    for (int m = 1; m < 64; m <<= 1) v += __shfl_xor(v, m);
    if ((threadIdx.x & 63) == 0) s4[threadIdx.x >> 6] = v;
    __syncthreads();
    if (threadIdx.x == 0) {
        float t = (s4[0] + s4[1] + s4[2] + s4[3]) * (1.0f / (float)NROW);
        atomicAdd(out, t);
    }
}

extern "C" void kernel_launch(void* const* d_in, const int* in_sizes, int n_in,
                              void* d_out, int out_size, void* d_ws, size_t ws_size,
                              hipStream_t stream) {
    const float* h1 = (const float*)d_in[0];
    const float* h2 = (const float*)d_in[1];
    float* out = (float*)d_out;

    char* ws = (char*)d_ws;
    unsigned char* z1b = (unsigned char*)ws;                             // 2 MB
    unsigned char* z2b = (unsigned char*)(ws + (size_t)NROW * DDIM);     // 2 MB
    float* sums = (float*)(ws + (size_t)2 * NROW * DDIM);
    float* rs1  = sums;
    float* rs2  = sums + NROW;
    float* rbr  = sums + 2 * NROW;
    float* rbc  = sums + 3 * NROW;
    float* diag = sums + 4 * NROW;

    hipMemsetAsync(out, 0, sizeof(float), stream);

    normalize_kernel<<<NROW / 4, 256, 0, stream>>>(h1, h2,
                                                   (unsigned int*)z1b, (unsigned int*)z2b,
                                                   diag, rs1, rs2, rbr, rbc);

    expsum_kernel<<<NBLOCKS, 256, 0, stream>>>(z1b, z2b, rs1, rs2, rbr, rbc);

    finalize_kernel<<<NROW / 256, 256, 0, stream>>>(rs1, rs2, rbr, rbc, diag, out);
}